// Round 9
// baseline (336.401 us; speedup 1.0000x reference)
//
#include <hip/hip_runtime.h>
#include <hip/hip_bf16.h>

#define N_NODES 50000
#define N_EDGES 800000
#define HDIM    128
#define N_RELS  24

// rel-padded tile capacity: 800000 + 24*63 -> 12524 tiles of 64
#define MAX_TILES  12524
#define SORTED_CAP (MAX_TILES * 64)
#define NSCAN_BLK  196          // ceil(50000/256)
#define TPB        8            // tiles per k_edgeA block (software-pipelined)

typedef __attribute__((ext_vector_type(8))) short bf16x8;
typedef __attribute__((ext_vector_type(4))) float f32x4;
typedef __attribute__((ext_vector_type(4))) unsigned int u32x4;

static __device__ __forceinline__ float bfbits2f(unsigned u) {
    return __uint_as_float(u << 16);            // bf16 -> f32 exact
}
static __device__ __forceinline__ unsigned f2bfbits(float x) {
    union { __hip_bfloat16 b; unsigned short u; } cv;
    cv.b = __float2bfloat16(x);                 // round-to-nearest
    return (unsigned)cv.u;
}

// msg/aggB rows use a PERMUTED column layout of 64 u32 words:
//   word j (j = l15*4 + c2):  lo = col c2*32 + l15,  hi = col c2*32 + 16 + l15
// k_agg is elementwise so it is layout-agnostic;
// k_selfA inverts: col = c*16+l15  ->  ushort idx = l15*8 + (c>>1)*2 + (c&1).

// ---------------- setup: convert + histogram ----------------

__global__ void k_setup(const float* __restrict__ h,
                        const float* __restrict__ W,
                        const float* __restrict__ Wl,
                        const int* __restrict__ rel,
                        const int* __restrict__ dst,
                        unsigned short* __restrict__ hb,
                        unsigned short* __restrict__ Wbt,
                        unsigned short* __restrict__ Wlbt,
                        int* __restrict__ degi,
                        int* __restrict__ meta)
{
    __shared__ int lh[N_RELS];
    if (threadIdx.x < N_RELS) lh[threadIdx.x] = 0;
    __syncthreads();

    int stride = gridDim.x * blockDim.x;
    int tid = blockIdx.x * blockDim.x + threadIdx.x;

    const float4* h4 = (const float4*)h;
    for (int i = tid; i < N_NODES * HDIM / 4; i += stride) {
        float4 v = h4[i];
        uint2 o;
        o.x = f2bfbits(v.x) | (f2bfbits(v.y) << 16);
        o.y = f2bfbits(v.z) | (f2bfbits(v.w) << 16);
        ((uint2*)hb)[i] = o;
    }
    // Wbt[r][e][k] = W[r][k][e], 4 k at a time
    for (int i = tid; i < N_RELS * HDIM * HDIM / 4; i += stride) {
        int r = i >> 12, rem = i & 4095;
        int e = rem >> 5, kq = rem & 31;
        const float* wp = W + (r << 14) + (kq << 9) + e;
        uint2 o;
        o.x = f2bfbits(wp[0])   | (f2bfbits(wp[128]) << 16);
        o.y = f2bfbits(wp[256]) | (f2bfbits(wp[384]) << 16);
        ((uint2*)Wbt)[i] = o;
    }
    for (int i = tid; i < HDIM * HDIM / 4; i += stride) {
        int e = i >> 5, kq = i & 31;
        const float* wp = Wl + (kq << 9) + e;
        uint2 o;
        o.x = f2bfbits(wp[0])   | (f2bfbits(wp[128]) << 16);
        o.y = f2bfbits(wp[256]) | (f2bfbits(wp[384]) << 16);
        ((uint2*)Wlbt)[i] = o;
    }
    // histogram (degi & meta pre-zeroed by hipMemsetAsync)
    for (int e = tid; e < N_EDGES; e += stride) {
        atomicAdd(&lh[rel[e]], 1);
        atomicAdd(&degi[dst[e]], 1);
    }
    __syncthreads();
    if (threadIdx.x < N_RELS) atomicAdd(&meta[threadIdx.x], lh[threadIdx.x]);
}

// ---------------- hierarchical dst scan (parallel) ----------------

__global__ __launch_bounds__(256) void k_bsum(const int* __restrict__ degi,
                                              int* __restrict__ bsum)
{
    int i = blockIdx.x * 256 + threadIdx.x;
    int v = (i < N_NODES) ? degi[i] : 0;
    #pragma unroll
    for (int d = 32; d > 0; d >>= 1) v += __shfl_down(v, d);
    __shared__ int ws4[4];
    int lane = threadIdx.x & 63, wv = threadIdx.x >> 6;
    if (lane == 0) ws4[wv] = v;
    __syncthreads();
    if (threadIdx.x == 0)
        bsum[blockIdx.x] = ws4[0] + ws4[1] + ws4[2] + ws4[3];
}

// 1 block: parallel scan of the 196 block sums + serial 24-entry rel scan
__global__ __launch_bounds__(256) void k_scan_misc(int* __restrict__ meta,
                                                   const int* __restrict__ bsum,
                                                   int* __restrict__ boff,
                                                   int* __restrict__ seg)
{
    __shared__ int wsum[4];
    int t = threadIdx.x;
    int v = (t < NSCAN_BLK) ? bsum[t] : 0;
    int lane = t & 63, wv = t >> 6;
    int x = v;
    #pragma unroll
    for (int d = 1; d < 64; d <<= 1) {
        int y = __shfl_up(x, d);
        if (lane >= d) x += y;
    }
    if (lane == 63) wsum[wv] = x;
    __syncthreads();
    int add = 0;
    for (int w = 0; w < wv; ++w) add += wsum[w];
    if (t < NSCAN_BLK) boff[t] = add + x - v;          // exclusive
    if (t == NSCAN_BLK - 1) seg[N_NODES] = add + x;    // total == N_EDGES

    if (t == 0) {   // rel scan: 24 iterations, trivial
        int run = 0;
        for (int r = 0; r < N_RELS; ++r) {
            int cnt = meta[r];
            meta[64 + r] = run;          // element base in sorted[]
            meta[96 + r] = run >> 6;     // tile base
            run += ((cnt + 63) >> 6) << 6;
        }
        meta[64 + N_RELS] = run;
        meta[96 + N_RELS] = run >> 6;    // total tiles
    }
}

__global__ __launch_bounds__(256) void k_seg(const int* __restrict__ degi,
                                             const int* __restrict__ boff,
                                             int* __restrict__ seg,
                                             int* __restrict__ cursor)
{
    int i = blockIdx.x * 256 + threadIdx.x;
    int lane = threadIdx.x & 63, wv = threadIdx.x >> 6;
    int v = (i < N_NODES) ? degi[i] : 0;
    int x = v;
    #pragma unroll
    for (int d = 1; d < 64; d <<= 1) {
        int y = __shfl_up(x, d);
        if (lane >= d) x += y;
    }
    __shared__ int wpart[4];
    if (lane == 63) wpart[wv] = x;
    __syncthreads();
    int add = 0;
    for (int w = 0; w < wv; ++w) add += wpart[w];
    int s = boff[blockIdx.x] + add + x - v;   // exclusive
    if (i < N_NODES) { seg[i] = s; cursor[i] = s; }
}

// ---------------- scatter: packed (src,slot) per rel-sorted position ----------------

__global__ void k_scatter(const int* __restrict__ rel,
                          const int* __restrict__ dst,
                          const int* __restrict__ src,
                          int* __restrict__ meta,
                          int* __restrict__ sorted,
                          int* __restrict__ cursor,
                          int2* __restrict__ edinfo,
                          int writeSorted)
{
    __shared__ int lh[N_RELS], lb[N_RELS];
    if (threadIdx.x < N_RELS) lh[threadIdx.x] = 0;
    __syncthreads();
    int e = blockIdx.x * blockDim.x + threadIdx.x;
    int r = 0, my = 0;
    bool valid = (e < N_EDGES);
    if (valid) {
        r = rel[e];
        my = atomicAdd(&lh[r], 1);
    }
    __syncthreads();
    if (threadIdx.x < N_RELS)
        lb[threadIdx.x] = atomicAdd(&meta[32 + threadIdx.x], lh[threadIdx.x]);
    __syncthreads();
    if (valid) {
        int pos = meta[64 + r] + lb[r] + my;
        if (writeSorted) sorted[pos] = e;             // path-B fallback only
        int slot = atomicAdd(&cursor[dst[e]], 1);
        edinfo[pos] = make_int2(src[e], slot);
    }
}

// ---------------- edge GEMM: 8 tiles/block, software-pipelined prefetch ----------------

__global__ __launch_bounds__(256) void k_edgeA(
    const unsigned short* __restrict__ hb,
    const unsigned short* __restrict__ Wbt,
    const int2* __restrict__ edinfo,
    const int* __restrict__ meta,
    unsigned int* __restrict__ msg)
{
    __shared__ __align__(16) unsigned char Ws[128 * 256];

    int ntiles = meta[96 + N_RELS];
    int b0 = blockIdx.x * TPB;
    if (b0 >= ntiles) return;
    int ntloc = ntiles - b0; if (ntloc > TPB) ntloc = TPB;

    int t = threadIdx.x;
    int lane = t & 63, wave = t >> 6;
    int l15 = lane & 15, l4 = lane >> 4;
    int arow = (wave << 4) + l15;

    int rptr = 0;
    while (b0 >= meta[96 + rptr + 1]) ++rptr;

    // current tile state (tile b0)
    int rA = rptr;
    int limA = meta[rA] - ((b0 - meta[96 + rA]) << 6);
    if (limA > 64) limA = 64;
    bf16x8 c0, c1, c2, c3;
    {
        int srow = (arow < limA) ? edinfo[(b0 << 6) + arow].x : 0;
        const char* ap = (const char*)hb + (size_t)srow * 256 + (l4 << 4);
        c0 = *(const bf16x8*)(ap);
        c1 = *(const bf16x8*)(ap + 64);
        c2 = *(const bf16x8*)(ap + 128);
        c3 = *(const bf16x8*)(ap + 192);
    }

    int rcur = -1;
    for (int bt = 0; bt < ntloc; ++bt) {
        int b = b0 + bt;
        bool havnext = (bt + 1 < ntloc);

        // prefetch tile bt+1 while current tile computes
        int rN = rA, limN = 0;
        bf16x8 n0 = c0, n1 = c1, n2 = c2, n3 = c3;
        if (havnext) {
            int bn = b + 1;
            while (bn >= meta[96 + rptr + 1]) ++rptr;
            rN = rptr;
            limN = meta[rN] - ((bn - meta[96 + rN]) << 6);
            if (limN > 64) limN = 64;
            int srow = (arow < limN) ? edinfo[(bn << 6) + arow].x : 0;
            const char* ap = (const char*)hb + (size_t)srow * 256 + (l4 << 4);
            n0 = *(const bf16x8*)(ap);
            n1 = *(const bf16x8*)(ap + 64);
            n2 = *(const bf16x8*)(ap + 128);
            n3 = *(const bf16x8*)(ap + 192);
        }

        if (rA != rcur) {            // block-uniform branch (rare: rel boundaries)
            if (bt > 0) __syncthreads();      // drain readers of old W
            int row = t >> 1, half = t & 1;
            const uint4* g = (const uint4*)((const char*)Wbt + (size_t)rA * 32768 + row * 256);
            unsigned sw = (row & 7) << 4;
            #pragma unroll
            for (int j = 0; j < 8; ++j) {
                int cb = (half << 7) + (j << 4);
                *(uint4*)(Ws + row * 256 + (cb ^ sw)) = g[cb >> 4];
            }
            rcur = rA;
            __syncthreads();
        }

        f32x4 acc[8];
        #pragma unroll
        for (int c = 0; c < 8; ++c) acc[c] = (f32x4)0.0f;

        #pragma unroll
        for (int kk = 0; kk < 4; ++kk) {
            int kb = (kk << 6) + (l4 << 4);
            bf16x8 a = (kk == 0) ? c0 : (kk == 1) ? c1 : (kk == 2) ? c2 : c3;
            #pragma unroll
            for (int c = 0; c < 8; ++c) {
                int brow = (c << 4) + l15;
                bf16x8 bb = *(const bf16x8*)(Ws + brow * 256 + (kb ^ ((brow & 7) << 4)));
                acc[c] = __builtin_amdgcn_mfma_f32_16x16x32_bf16(a, bb, acc[c], 0, 0, 0);
            }
        }

        // store: permuted pack, 16B contiguous per lane per edge-row
        #pragma unroll
        for (int i = 0; i < 4; ++i) {
            int m = (wave << 4) + (l4 << 2) + i;
            if (m < limA) {
                int slot = edinfo[(b << 6) + m].y;     // L1-hot
                u32x4 o;
                o.x = f2bfbits(acc[0][i]) | (f2bfbits(acc[1][i]) << 16);
                o.y = f2bfbits(acc[2][i]) | (f2bfbits(acc[3][i]) << 16);
                o.z = f2bfbits(acc[4][i]) | (f2bfbits(acc[5][i]) << 16);
                o.w = f2bfbits(acc[6][i]) | (f2bfbits(acc[7][i]) << 16);
                __builtin_nontemporal_store(o,
                    (u32x4*)((char*)msg + (size_t)slot * 256 + (l15 << 4)));
            }
        }

        c0 = n0; c1 = n1; c2 = n2; c3 = n3;
        rA = rN; limA = limN;
    }
}

// ---------------- segment mean: one wave per node ----------------

__global__ __launch_bounds__(256) void k_agg(
    const unsigned int* __restrict__ msg,
    const int* __restrict__ seg,
    unsigned short* __restrict__ aggB)
{
    int wv = threadIdx.x >> 6, lane = threadIdx.x & 63;
    int n = blockIdx.x * 4 + wv;
    if (n >= N_NODES) return;
    int s0 = seg[n], s1 = seg[n + 1];
    int deg = s1 - s0;
    int l4 = lane >> 4, l15 = lane & 15;

    float acc[8] = {0, 0, 0, 0, 0, 0, 0, 0};
    const char* base = (const char*)msg + (size_t)s0 * 256;
    int nit = (deg + 3) >> 2;
    for (int it = 0; it < nit; ++it) {
        if (it * 4 + l4 < deg) {
            u32x4 v = __builtin_nontemporal_load(
                (const u32x4*)(base + (size_t)it * 1024 + lane * 16));
            acc[0] += bfbits2f(v.x & 0xffff); acc[1] += bfbits2f(v.x >> 16);
            acc[2] += bfbits2f(v.y & 0xffff); acc[3] += bfbits2f(v.y >> 16);
            acc[4] += bfbits2f(v.z & 0xffff); acc[5] += bfbits2f(v.z >> 16);
            acc[6] += bfbits2f(v.w & 0xffff); acc[7] += bfbits2f(v.w >> 16);
        }
    }
    #pragma unroll
    for (int k = 0; k < 8; ++k) {
        acc[k] += __shfl_xor(acc[k], 16);
        acc[k] += __shfl_xor(acc[k], 32);
    }
    if (l4 == 0) {
        float inv = 1.0f / fmaxf((float)deg, 1.0f);
        u32x4 u;
        u.x = f2bfbits(acc[0] * inv) | (f2bfbits(acc[1] * inv) << 16);
        u.y = f2bfbits(acc[2] * inv) | (f2bfbits(acc[3] * inv) << 16);
        u.z = f2bfbits(acc[4] * inv) | (f2bfbits(acc[5] * inv) << 16);
        u.w = f2bfbits(acc[6] * inv) | (f2bfbits(acc[7] * inv) << 16);
        *(u32x4*)((char*)aggB + (size_t)n * 256 + l15 * 16) = u;
    }
}

// ---------------- self-loop GEMM + agg + bias + relu ----------------

__global__ __launch_bounds__(256) void k_selfA(
    const unsigned short* __restrict__ hb,
    const unsigned short* __restrict__ Wlbt,
    const float* __restrict__ bias,
    const unsigned short* __restrict__ aggB,
    float* __restrict__ out)
{
    __shared__ __align__(16) unsigned char Ws[128 * 256];
    __shared__ float biasS[128];

    int b = blockIdx.x, t = threadIdx.x;
    int n0 = b << 6;
    int lane = t & 63, wave = t >> 6;
    int l15 = lane & 15, l4 = lane >> 4;

    if (t < 128) biasS[t] = bias[t];

    int arow = (wave << 4) + l15;
    int va = n0 + arow; if (va > N_NODES - 1) va = N_NODES - 1;
    const char* ap = (const char*)hb + (size_t)va * 256 + (l4 << 4);
    bf16x8 a0 = *(const bf16x8*)(ap);
    bf16x8 a1 = *(const bf16x8*)(ap + 64);
    bf16x8 a2 = *(const bf16x8*)(ap + 128);
    bf16x8 a3 = *(const bf16x8*)(ap + 192);

    {
        int row = t >> 1, half = t & 1;
        const uint4* g = (const uint4*)((const char*)Wlbt + row * 256);
        unsigned sw = (row & 7) << 4;
        #pragma unroll
        for (int j = 0; j < 8; ++j) {
            int cb = (half << 7) + (j << 4);
            *(uint4*)(Ws + row * 256 + (cb ^ sw)) = g[cb >> 4];
        }
    }
    __syncthreads();

    f32x4 acc[8];
    #pragma unroll
    for (int c = 0; c < 8; ++c) acc[c] = (f32x4)0.0f;

    #pragma unroll
    for (int kk = 0; kk < 4; ++kk) {
        int kb = (kk << 6) + (l4 << 4);
        bf16x8 a = (kk == 0) ? a0 : (kk == 1) ? a1 : (kk == 2) ? a2 : a3;
        #pragma unroll
        for (int c = 0; c < 8; ++c) {
            int brow = (c << 4) + l15;
            bf16x8 bb = *(const bf16x8*)(Ws + brow * 256 + (kb ^ ((brow & 7) << 4)));
            acc[c] = __builtin_amdgcn_mfma_f32_16x16x32_bf16(a, bb, acc[c], 0, 0, 0);
        }
    }

    #pragma unroll
    for (int c = 0; c < 8; ++c) {
        #pragma unroll
        for (int i = 0; i < 4; ++i) {
            int m = (wave << 4) + (l4 << 2) + i;
            int v = n0 + m;
            if (v < N_NODES) {
                int col = (c << 4) + l15;
                // inverse perm read of aggB
                float ag = bfbits2f(aggB[(size_t)v * 128 + l15 * 8 + ((c >> 1) << 1) + (c & 1)]);
                float val = acc[c][i] + ag + biasS[col];
                out[(size_t)v * 128 + col] = fmaxf(val, 0.0f);
            }
        }
    }
}

// ---------------- path B fallback: atomic aggregation into out ----------------

__global__ __launch_bounds__(256) void k_edgeB(
    const unsigned short* __restrict__ hb,
    const unsigned short* __restrict__ Wbt,
    const int* __restrict__ src,
    const int* __restrict__ dst,
    const int* __restrict__ sorted,
    const int* __restrict__ meta,
    float* __restrict__ agg)
{
    __shared__ __align__(16) unsigned char Ws[128 * 256];

    int b = blockIdx.x;
    if (b >= meta[96 + N_RELS]) return;
    int r = 0;
    while (b >= meta[96 + r + 1]) ++r;
    int lbase = (b - meta[96 + r]) << 6;
    int lim = meta[r] - lbase;
    if (lim > 64) lim = 64;

    int t = threadIdx.x;
    int lane = t & 63, wave = t >> 6;
    int l15 = lane & 15, l4 = lane >> 4;

    int arow = (wave << 4) + l15;
    int srow = 0;
    if (arow < lim) srow = src[sorted[(b << 6) + arow]];
    const char* ap = (const char*)hb + (size_t)srow * 256 + (l4 << 4);
    bf16x8 a0 = *(const bf16x8*)(ap);
    bf16x8 a1 = *(const bf16x8*)(ap + 64);
    bf16x8 a2 = *(const bf16x8*)(ap + 128);
    bf16x8 a3 = *(const bf16x8*)(ap + 192);

    {
        int row = t >> 1, half = t & 1;
        const uint4* g = (const uint4*)((const char*)Wbt + (size_t)r * 32768 + row * 256);
        unsigned sw = (row & 7) << 4;
        #pragma unroll
        for (int j = 0; j < 8; ++j) {
            int cb = (half << 7) + (j << 4);
            *(uint4*)(Ws + row * 256 + (cb ^ sw)) = g[cb >> 4];
        }
    }
    __syncthreads();

    f32x4 acc[8];
    #pragma unroll
    for (int c = 0; c < 8; ++c) acc[c] = (f32x4)0.0f;

    #pragma unroll
    for (int kk = 0; kk < 4; ++kk) {
        int kb = (kk << 6) + (l4 << 4);
        bf16x8 a = (kk == 0) ? a0 : (kk == 1) ? a1 : (kk == 2) ? a2 : a3;
        #pragma unroll
        for (int c = 0; c < 8; ++c) {
            int brow = (c << 4) + l15;
            bf16x8 bb = *(const bf16x8*)(Ws + brow * 256 + (kb ^ ((brow & 7) << 4)));
            acc[c] = __builtin_amdgcn_mfma_f32_16x16x32_bf16(a, bb, acc[c], 0, 0, 0);
        }
    }

    #pragma unroll
    for (int i = 0; i < 4; ++i) {
        int m = (wave << 4) + (l4 << 2) + i;
        if (m < lim) {
            int d = dst[sorted[(b << 6) + m]];
            #pragma unroll
            for (int c = 0; c < 8; ++c)
                atomicAdd(&agg[(size_t)d * 128 + (c << 4) + l15], acc[c][i]);
        }
    }
}

__global__ __launch_bounds__(256) void k_selfB(
    const unsigned short* __restrict__ hb,
    const unsigned short* __restrict__ Wlbt,
    const float* __restrict__ bias,
    const int* __restrict__ degi,
    float* __restrict__ agg)
{
    __shared__ __align__(16) unsigned char Ws[128 * 256];
    __shared__ float biasS[128];

    int b = blockIdx.x, t = threadIdx.x;
    int n0 = b << 6;
    int lane = t & 63, wave = t >> 6;
    int l15 = lane & 15, l4 = lane >> 4;

    if (t < 128) biasS[t] = bias[t];

    int arow = (wave << 4) + l15;
    int va = n0 + arow; if (va > N_NODES - 1) va = N_NODES - 1;
    const char* ap = (const char*)hb + (size_t)va * 256 + (l4 << 4);
    bf16x8 a0 = *(const bf16x8*)(ap);
    bf16x8 a1 = *(const bf16x8*)(ap + 64);
    bf16x8 a2 = *(const bf16x8*)(ap + 128);
    bf16x8 a3 = *(const bf16x8*)(ap + 192);

    {
        int row = t >> 1, half = t & 1;
        const uint4* g = (const uint4*)((const char*)Wlbt + row * 256);
        unsigned sw = (row & 7) << 4;
        #pragma unroll
        for (int j = 0; j < 8; ++j) {
            int cb = (half << 7) + (j << 4);
            *(uint4*)(Ws + row * 256 + (cb ^ sw)) = g[cb >> 4];
        }
    }
    __syncthreads();

    f32x4 acc[8];
    #pragma unroll
    for (int c = 0; c < 8; ++c) acc[c] = (f32x4)0.0f;

    #pragma unroll
    for (int kk = 0; kk < 4; ++kk) {
        int kb = (kk << 6) + (l4 << 4);
        bf16x8 a = (kk == 0) ? a0 : (kk == 1) ? a1 : (kk == 2) ? a2 : a3;
        #pragma unroll
        for (int c = 0; c < 8; ++c) {
            int brow = (c << 4) + l15;
            bf16x8 bb = *(const bf16x8*)(Ws + brow * 256 + (kb ^ ((brow & 7) << 4)));
            acc[c] = __builtin_amdgcn_mfma_f32_16x16x32_bf16(a, bb, acc[c], 0, 0, 0);
        }
    }

    #pragma unroll
    for (int c = 0; c < 8; ++c) {
        #pragma unroll
        for (int i = 0; i < 4; ++i) {
            int m = (wave << 4) + (l4 << 2) + i;
            int v = n0 + m;
            if (v < N_NODES) {
                int col = (c << 4) + l15;
                float inv = 1.0f / fmaxf((float)degi[v], 1.0f);
                float val = acc[c][i] + agg[(size_t)v * 128 + col] * inv + biasS[col];
                agg[(size_t)v * 128 + col] = fmaxf(val, 0.0f);
            }
        }
    }
}

// ---------------- launch ----------------

extern "C" void kernel_launch(void* const* d_in, const int* in_sizes, int n_in,
                              void* d_out, int out_size, void* d_ws, size_t ws_size,
                              hipStream_t stream)
{
    (void)in_sizes; (void)n_in; (void)out_size;

    const float* h    = (const float*)d_in[0];
    const float* W    = (const float*)d_in[1];
    const float* Wl   = (const float*)d_in[2];
    const float* bias = (const float*)d_in[3];
    const int*   src  = (const int*)d_in[4];
    const int*   dst  = (const int*)d_in[5];
    const int*   rel  = (const int*)d_in[6];
    float* out = (float*)d_out;

    char* ws = (char*)d_ws;
    size_t off = 0;
    auto take = [&](size_t bytes) -> char* {
        char* p = ws + off;
        off += (bytes + 255) & ~(size_t)255;
        return p;
    };
    unsigned short* hb   = (unsigned short*)take((size_t)N_NODES * HDIM * 2);
    unsigned short* Wbt  = (unsigned short*)take((size_t)N_RELS * HDIM * HDIM * 2);
    unsigned short* Wlbt = (unsigned short*)take((size_t)HDIM * HDIM * 2);
    int*   degi    = (int*)take((size_t)N_NODES * 4);
    int*   meta    = (int*)take(1024);
    int*   sorted  = (int*)take((size_t)SORTED_CAP * 4);
    int*   seg     = (int*)take((size_t)(N_NODES + 1) * 4);
    int*   cursor  = (int*)take((size_t)N_NODES * 4);
    int*   bsum    = (int*)take((size_t)NSCAN_BLK * 4);
    int*   boff    = (int*)take((size_t)NSCAN_BLK * 4);
    int2*  edinfo  = (int2*)take((size_t)SORTED_CAP * 8);
    unsigned int*   msg  = (unsigned int*)take((size_t)N_EDGES * HDIM * 2);
    unsigned short* aggB = (unsigned short*)take((size_t)N_NODES * HDIM * 2);
    size_t big_need = off;

    bool pathA = (ws_size >= big_need);

    size_t zbytes = (size_t)((char*)meta - (char*)degi) + 1024;
    (void)hipMemsetAsync(degi, 0, zbytes, stream);

    k_setup<<<2048, 256, 0, stream>>>(h, W, Wl, rel, dst, hb, Wbt, Wlbt, degi, meta);
    k_bsum<<<NSCAN_BLK, 256, 0, stream>>>(degi, bsum);
    k_scan_misc<<<1, 256, 0, stream>>>(meta, bsum, boff, seg);
    k_seg<<<NSCAN_BLK, 256, 0, stream>>>(degi, boff, seg, cursor);
    k_scatter<<<(N_EDGES + 255) / 256, 256, 0, stream>>>(rel, dst, src, meta, sorted, cursor,
                                                         edinfo, pathA ? 0 : 1);

    if (pathA) {
        k_edgeA<<<(MAX_TILES + TPB - 1) / TPB, 256, 0, stream>>>(hb, Wbt, edinfo, meta, msg);
        k_agg<<<(N_NODES + 3) / 4, 256, 0, stream>>>(msg, seg, aggB);
        k_selfA<<<(N_NODES + 63) / 64, 256, 0, stream>>>(hb, Wlbt, bias, aggB, out);
    } else {
        (void)hipMemsetAsync(out, 0, (size_t)N_NODES * HDIM * 4, stream);
        k_edgeB<<<MAX_TILES, 256, 0, stream>>>(hb, Wbt, src, dst, sorted, meta, out);
        k_selfB<<<(N_NODES + 63) / 64, 256, 0, stream>>>(hb, Wlbt, bias, degi, out);
    }
}

// Round 10
// 322.578 us; speedup vs baseline: 1.0429x; 1.0429x over previous
//
#include <hip/hip_runtime.h>
#include <hip/hip_bf16.h>

#define N_NODES 50000
#define N_EDGES 800000
#define HDIM    128
#define N_RELS  24

// rel-padded tile capacity (tiles of 128): 800000 + 24*127 -> 6274 tiles
#define MAX_TILES  6274
#define SORTED_CAP (MAX_TILES * 128)
#define NSCAN_BLK  196          // ceil(50000/256)
#define TPB        2            // 128-edge tiles per k_edgeA block

typedef __attribute__((ext_vector_type(8))) short bf16x8;
typedef __attribute__((ext_vector_type(4))) float f32x4;
typedef __attribute__((ext_vector_type(4))) unsigned int u32x4;

static __device__ __forceinline__ float bfbits2f(unsigned u) {
    return __uint_as_float(u << 16);            // bf16 -> f32 exact
}
static __device__ __forceinline__ unsigned f2bfbits(float x) {
    union { __hip_bfloat16 b; unsigned short u; } cv;
    cv.b = __float2bfloat16(x);                 // round-to-nearest
    return (unsigned)cv.u;
}

// msg/aggB rows use a PERMUTED column layout of 64 u32 words:
//   word j (j = l15*4 + c2):  lo = col c2*32 + l15,  hi = col c2*32 + 16 + l15
// k_agg is elementwise so it is layout-agnostic;
// k_selfA inverts: col = c*16+l15  ->  ushort idx = l15*8 + (c>>1)*2 + (c&1).

// ---------------- setup: convert + histogram ----------------

__global__ void k_setup(const float* __restrict__ h,
                        const float* __restrict__ W,
                        const float* __restrict__ Wl,
                        const int* __restrict__ rel,
                        const int* __restrict__ dst,
                        unsigned short* __restrict__ hb,
                        unsigned short* __restrict__ Wbt,
                        unsigned short* __restrict__ Wlbt,
                        int* __restrict__ degi,
                        int* __restrict__ meta)
{
    __shared__ int lh[N_RELS];
    if (threadIdx.x < N_RELS) lh[threadIdx.x] = 0;
    __syncthreads();

    int stride = gridDim.x * blockDim.x;
    int tid = blockIdx.x * blockDim.x + threadIdx.x;

    const float4* h4 = (const float4*)h;
    for (int i = tid; i < N_NODES * HDIM / 4; i += stride) {
        float4 v = h4[i];
        uint2 o;
        o.x = f2bfbits(v.x) | (f2bfbits(v.y) << 16);
        o.y = f2bfbits(v.z) | (f2bfbits(v.w) << 16);
        ((uint2*)hb)[i] = o;
    }
    // Wbt[r][e][k] = W[r][k][e], 4 k at a time
    for (int i = tid; i < N_RELS * HDIM * HDIM / 4; i += stride) {
        int r = i >> 12, rem = i & 4095;
        int e = rem >> 5, kq = rem & 31;
        const float* wp = W + (r << 14) + (kq << 9) + e;
        uint2 o;
        o.x = f2bfbits(wp[0])   | (f2bfbits(wp[128]) << 16);
        o.y = f2bfbits(wp[256]) | (f2bfbits(wp[384]) << 16);
        ((uint2*)Wbt)[i] = o;
    }
    for (int i = tid; i < HDIM * HDIM / 4; i += stride) {
        int e = i >> 5, kq = i & 31;
        const float* wp = Wl + (kq << 9) + e;
        uint2 o;
        o.x = f2bfbits(wp[0])   | (f2bfbits(wp[128]) << 16);
        o.y = f2bfbits(wp[256]) | (f2bfbits(wp[384]) << 16);
        ((uint2*)Wlbt)[i] = o;
    }
    // histogram (degi & meta pre-zeroed by hipMemsetAsync)
    for (int e = tid; e < N_EDGES; e += stride) {
        atomicAdd(&lh[rel[e]], 1);
        atomicAdd(&degi[dst[e]], 1);
    }
    __syncthreads();
    if (threadIdx.x < N_RELS) atomicAdd(&meta[threadIdx.x], lh[threadIdx.x]);
}

// ---------------- hierarchical dst scan (parallel) ----------------

__global__ __launch_bounds__(256) void k_bsum(const int* __restrict__ degi,
                                              int* __restrict__ bsum)
{
    int i = blockIdx.x * 256 + threadIdx.x;
    int v = (i < N_NODES) ? degi[i] : 0;
    #pragma unroll
    for (int d = 32; d > 0; d >>= 1) v += __shfl_down(v, d);
    __shared__ int ws4[4];
    int lane = threadIdx.x & 63, wv = threadIdx.x >> 6;
    if (lane == 0) ws4[wv] = v;
    __syncthreads();
    if (threadIdx.x == 0)
        bsum[blockIdx.x] = ws4[0] + ws4[1] + ws4[2] + ws4[3];
}

// 1 block: parallel scan of the 196 block sums + serial 24-entry rel scan (tiles of 128)
__global__ __launch_bounds__(256) void k_scan_misc(int* __restrict__ meta,
                                                   const int* __restrict__ bsum,
                                                   int* __restrict__ boff,
                                                   int* __restrict__ seg)
{
    __shared__ int wsum[4];
    int t = threadIdx.x;
    int v = (t < NSCAN_BLK) ? bsum[t] : 0;
    int lane = t & 63, wv = t >> 6;
    int x = v;
    #pragma unroll
    for (int d = 1; d < 64; d <<= 1) {
        int y = __shfl_up(x, d);
        if (lane >= d) x += y;
    }
    if (lane == 63) wsum[wv] = x;
    __syncthreads();
    int add = 0;
    for (int w = 0; w < wv; ++w) add += wsum[w];
    if (t < NSCAN_BLK) boff[t] = add + x - v;          // exclusive
    if (t == NSCAN_BLK - 1) seg[N_NODES] = add + x;    // total == N_EDGES

    if (t == 0) {   // rel scan: 24 iterations, trivial. tiles of 128
        int run = 0;
        for (int r = 0; r < N_RELS; ++r) {
            int cnt = meta[r];
            meta[64 + r] = run;          // element base in edinfo[]
            meta[96 + r] = run >> 7;     // tile base (128-edge tiles)
            run += ((cnt + 127) >> 7) << 7;
        }
        meta[64 + N_RELS] = run;
        meta[96 + N_RELS] = run >> 7;    // total tiles
    }
}

__global__ __launch_bounds__(256) void k_seg(const int* __restrict__ degi,
                                             const int* __restrict__ boff,
                                             int* __restrict__ seg,
                                             int* __restrict__ cursor)
{
    int i = blockIdx.x * 256 + threadIdx.x;
    int lane = threadIdx.x & 63, wv = threadIdx.x >> 6;
    int v = (i < N_NODES) ? degi[i] : 0;
    int x = v;
    #pragma unroll
    for (int d = 1; d < 64; d <<= 1) {
        int y = __shfl_up(x, d);
        if (lane >= d) x += y;
    }
    __shared__ int wpart[4];
    if (lane == 63) wpart[wv] = x;
    __syncthreads();
    int add = 0;
    for (int w = 0; w < wv; ++w) add += wpart[w];
    int s = boff[blockIdx.x] + add + x - v;   // exclusive
    if (i < N_NODES) { seg[i] = s; cursor[i] = s; }
}

// ---------------- scatter: packed (src,slot) per rel-sorted position ----------------

__global__ void k_scatter(const int* __restrict__ rel,
                          const int* __restrict__ dst,
                          const int* __restrict__ src,
                          int* __restrict__ meta,
                          int* __restrict__ sorted,
                          int* __restrict__ cursor,
                          int2* __restrict__ edinfo,
                          int writeSorted)
{
    __shared__ int lh[N_RELS], lb[N_RELS];
    if (threadIdx.x < N_RELS) lh[threadIdx.x] = 0;
    __syncthreads();
    int e = blockIdx.x * blockDim.x + threadIdx.x;
    int r = 0, my = 0;
    bool valid = (e < N_EDGES);
    if (valid) {
        r = rel[e];
        my = atomicAdd(&lh[r], 1);
    }
    __syncthreads();
    if (threadIdx.x < N_RELS)
        lb[threadIdx.x] = atomicAdd(&meta[32 + threadIdx.x], lh[threadIdx.x]);
    __syncthreads();
    if (valid) {
        int pos = meta[64 + r] + lb[r] + my;
        if (writeSorted) sorted[pos] = dst[e];        // path-B fallback only (stores dst)
        int slot = atomicAdd(&cursor[dst[e]], 1);
        edinfo[pos] = make_int2(src[e], slot);
    }
}

// ---------------- edge GEMM: 512 thr, 128-edge tiles, shared W stage ----------------

__global__ __launch_bounds__(512) void k_edgeA(
    const unsigned short* __restrict__ hb,
    const unsigned short* __restrict__ Wbt,
    const int2* __restrict__ edinfo,
    const int* __restrict__ meta,
    unsigned int* __restrict__ msg)
{
    __shared__ __align__(16) unsigned char Ws[128 * 256];

    int ntiles = meta[96 + N_RELS];
    int b0 = blockIdx.x * TPB;
    if (b0 >= ntiles) return;
    int ntloc = ntiles - b0; if (ntloc > TPB) ntloc = TPB;

    int t = threadIdx.x;
    int lane = t & 63, wave = t >> 6;          // wave 0..7
    int l15 = lane & 15, l4 = lane >> 4;
    int arow = (wave << 4) + l15;              // edge row in tile, 0..127

    int rptr = 0;
    while (b0 >= meta[96 + rptr + 1]) ++rptr;
    int rcur = -1;

    for (int bt = 0; bt < ntloc; ++bt) {
        int b = b0 + bt;
        while (b >= meta[96 + rptr + 1]) ++rptr;
        int r = rptr;
        int lim = meta[r] - ((b - meta[96 + r]) << 7);
        if (lim > 128) lim = 128;

        if (r != rcur) {            // block-uniform (rel boundary)
            if (bt > 0) __syncthreads();      // drain readers of old W
            int row = t >> 2, q = t & 3;      // 4 threads per row, 64B each
            const uint4* g = (const uint4*)((const char*)Wbt + (size_t)r * 32768 + row * 256);
            unsigned sw = (row & 7) << 4;
            #pragma unroll
            for (int j = 0; j < 4; ++j) {
                int cb = (q << 6) + (j << 4);
                *(uint4*)(Ws + row * 256 + (cb ^ sw)) = g[cb >> 4];
            }
            rcur = r;
            __syncthreads();
        }

        // A fragments: coalesced edinfo read + hb row gather (L2/L3 resident)
        int srow = (arow < lim) ? edinfo[(b << 7) + arow].x : 0;
        const char* ap = (const char*)hb + (size_t)srow * 256 + (l4 << 4);
        bf16x8 a0 = *(const bf16x8*)(ap);
        bf16x8 a1 = *(const bf16x8*)(ap + 64);
        bf16x8 a2 = *(const bf16x8*)(ap + 128);
        bf16x8 a3 = *(const bf16x8*)(ap + 192);

        f32x4 acc[8];
        #pragma unroll
        for (int c = 0; c < 8; ++c) acc[c] = (f32x4)0.0f;

        #pragma unroll
        for (int kk = 0; kk < 4; ++kk) {
            int kb = (kk << 6) + (l4 << 4);
            bf16x8 a = (kk == 0) ? a0 : (kk == 1) ? a1 : (kk == 2) ? a2 : a3;
            #pragma unroll
            for (int c = 0; c < 8; ++c) {
                int brow = (c << 4) + l15;
                bf16x8 bb = *(const bf16x8*)(Ws + brow * 256 + (kb ^ ((brow & 7) << 4)));
                acc[c] = __builtin_amdgcn_mfma_f32_16x16x32_bf16(a, bb, acc[c], 0, 0, 0);
            }
        }

        // store: permuted pack, 16B contiguous per lane per edge-row
        #pragma unroll
        for (int i = 0; i < 4; ++i) {
            int m = (wave << 4) + (l4 << 2) + i;
            if (m < lim) {
                int slot = edinfo[(b << 7) + m].y;     // L1-hot
                u32x4 o;
                o.x = f2bfbits(acc[0][i]) | (f2bfbits(acc[1][i]) << 16);
                o.y = f2bfbits(acc[2][i]) | (f2bfbits(acc[3][i]) << 16);
                o.z = f2bfbits(acc[4][i]) | (f2bfbits(acc[5][i]) << 16);
                o.w = f2bfbits(acc[6][i]) | (f2bfbits(acc[7][i]) << 16);
                __builtin_nontemporal_store(o,
                    (u32x4*)((char*)msg + (size_t)slot * 256 + (l15 << 4)));
            }
        }
    }
}

// ---------------- segment mean: one wave per node ----------------

__global__ __launch_bounds__(256) void k_agg(
    const unsigned int* __restrict__ msg,
    const int* __restrict__ seg,
    unsigned short* __restrict__ aggB)
{
    int wv = threadIdx.x >> 6, lane = threadIdx.x & 63;
    int n = blockIdx.x * 4 + wv;
    if (n >= N_NODES) return;
    int s0 = seg[n], s1 = seg[n + 1];
    int deg = s1 - s0;
    int l4 = lane >> 4, l15 = lane & 15;

    float acc[8] = {0, 0, 0, 0, 0, 0, 0, 0};
    const char* base = (const char*)msg + (size_t)s0 * 256;
    int nit = (deg + 3) >> 2;
    for (int it = 0; it < nit; ++it) {
        if (it * 4 + l4 < deg) {
            u32x4 v = __builtin_nontemporal_load(
                (const u32x4*)(base + (size_t)it * 1024 + lane * 16));
            acc[0] += bfbits2f(v.x & 0xffff); acc[1] += bfbits2f(v.x >> 16);
            acc[2] += bfbits2f(v.y & 0xffff); acc[3] += bfbits2f(v.y >> 16);
            acc[4] += bfbits2f(v.z & 0xffff); acc[5] += bfbits2f(v.z >> 16);
            acc[6] += bfbits2f(v.w & 0xffff); acc[7] += bfbits2f(v.w >> 16);
        }
    }
    #pragma unroll
    for (int k = 0; k < 8; ++k) {
        acc[k] += __shfl_xor(acc[k], 16);
        acc[k] += __shfl_xor(acc[k], 32);
    }
    if (l4 == 0) {
        float inv = 1.0f / fmaxf((float)deg, 1.0f);
        u32x4 u;
        u.x = f2bfbits(acc[0] * inv) | (f2bfbits(acc[1] * inv) << 16);
        u.y = f2bfbits(acc[2] * inv) | (f2bfbits(acc[3] * inv) << 16);
        u.z = f2bfbits(acc[4] * inv) | (f2bfbits(acc[5] * inv) << 16);
        u.w = f2bfbits(acc[6] * inv) | (f2bfbits(acc[7] * inv) << 16);
        *(u32x4*)((char*)aggB + (size_t)n * 256 + l15 * 16) = u;
    }
}

// ---------------- self-loop GEMM + agg + bias + relu ----------------

__global__ __launch_bounds__(256) void k_selfA(
    const unsigned short* __restrict__ hb,
    const unsigned short* __restrict__ Wlbt,
    const float* __restrict__ bias,
    const unsigned short* __restrict__ aggB,
    float* __restrict__ out)
{
    __shared__ __align__(16) unsigned char Ws[128 * 256];
    __shared__ float biasS[128];

    int b = blockIdx.x, t = threadIdx.x;
    int n0 = b << 6;
    int lane = t & 63, wave = t >> 6;
    int l15 = lane & 15, l4 = lane >> 4;

    if (t < 128) biasS[t] = bias[t];

    int arow = (wave << 4) + l15;
    int va = n0 + arow; if (va > N_NODES - 1) va = N_NODES - 1;
    const char* ap = (const char*)hb + (size_t)va * 256 + (l4 << 4);
    bf16x8 a0 = *(const bf16x8*)(ap);
    bf16x8 a1 = *(const bf16x8*)(ap + 64);
    bf16x8 a2 = *(const bf16x8*)(ap + 128);
    bf16x8 a3 = *(const bf16x8*)(ap + 192);

    {
        int row = t >> 1, half = t & 1;
        const uint4* g = (const uint4*)((const char*)Wlbt + row * 256);
        unsigned sw = (row & 7) << 4;
        #pragma unroll
        for (int j = 0; j < 8; ++j) {
            int cb = (half << 7) + (j << 4);
            *(uint4*)(Ws + row * 256 + (cb ^ sw)) = g[cb >> 4];
        }
    }
    __syncthreads();

    f32x4 acc[8];
    #pragma unroll
    for (int c = 0; c < 8; ++c) acc[c] = (f32x4)0.0f;

    #pragma unroll
    for (int kk = 0; kk < 4; ++kk) {
        int kb = (kk << 6) + (l4 << 4);
        bf16x8 a = (kk == 0) ? a0 : (kk == 1) ? a1 : (kk == 2) ? a2 : a3;
        #pragma unroll
        for (int c = 0; c < 8; ++c) {
            int brow = (c << 4) + l15;
            bf16x8 bb = *(const bf16x8*)(Ws + brow * 256 + (kb ^ ((brow & 7) << 4)));
            acc[c] = __builtin_amdgcn_mfma_f32_16x16x32_bf16(a, bb, acc[c], 0, 0, 0);
        }
    }

    #pragma unroll
    for (int c = 0; c < 8; ++c) {
        #pragma unroll
        for (int i = 0; i < 4; ++i) {
            int m = (wave << 4) + (l4 << 2) + i;
            int v = n0 + m;
            if (v < N_NODES) {
                int col = (c << 4) + l15;
                // inverse perm read of aggB
                float ag = bfbits2f(aggB[(size_t)v * 128 + l15 * 8 + ((c >> 1) << 1) + (c & 1)]);
                float val = acc[c][i] + ag + biasS[col];
                out[(size_t)v * 128 + col] = fmaxf(val, 0.0f);
            }
        }
    }
}

// ---------------- path B fallback: atomic aggregation into out ----------------

__global__ __launch_bounds__(512) void k_edgeB(
    const unsigned short* __restrict__ hb,
    const unsigned short* __restrict__ Wbt,
    const int2* __restrict__ edinfo,
    const int* __restrict__ sorted,          // holds dst per rel-sorted position
    const int* __restrict__ meta,
    float* __restrict__ agg)
{
    __shared__ __align__(16) unsigned char Ws[128 * 256];

    int b = blockIdx.x;
    if (b >= meta[96 + N_RELS]) return;
    int r = 0;
    while (b >= meta[96 + r + 1]) ++r;
    int lim = meta[r] - ((b - meta[96 + r]) << 7);
    if (lim > 128) lim = 128;

    int t = threadIdx.x;
    int lane = t & 63, wave = t >> 6;
    int l15 = lane & 15, l4 = lane >> 4;
    int arow = (wave << 4) + l15;

    int srow = (arow < lim) ? edinfo[(b << 7) + arow].x : 0;
    const char* ap = (const char*)hb + (size_t)srow * 256 + (l4 << 4);
    bf16x8 a0 = *(const bf16x8*)(ap);
    bf16x8 a1 = *(const bf16x8*)(ap + 64);
    bf16x8 a2 = *(const bf16x8*)(ap + 128);
    bf16x8 a3 = *(const bf16x8*)(ap + 192);

    {
        int row = t >> 2, q = t & 3;
        const uint4* g = (const uint4*)((const char*)Wbt + (size_t)r * 32768 + row * 256);
        unsigned sw = (row & 7) << 4;
        #pragma unroll
        for (int j = 0; j < 4; ++j) {
            int cb = (q << 6) + (j << 4);
            *(uint4*)(Ws + row * 256 + (cb ^ sw)) = g[cb >> 4];
        }
    }
    __syncthreads();

    f32x4 acc[8];
    #pragma unroll
    for (int c = 0; c < 8; ++c) acc[c] = (f32x4)0.0f;

    #pragma unroll
    for (int kk = 0; kk < 4; ++kk) {
        int kb = (kk << 6) + (l4 << 4);
        bf16x8 a = (kk == 0) ? a0 : (kk == 1) ? a1 : (kk == 2) ? a2 : a3;
        #pragma unroll
        for (int c = 0; c < 8; ++c) {
            int brow = (c << 4) + l15;
            bf16x8 bb = *(const bf16x8*)(Ws + brow * 256 + (kb ^ ((brow & 7) << 4)));
            acc[c] = __builtin_amdgcn_mfma_f32_16x16x32_bf16(a, bb, acc[c], 0, 0, 0);
        }
    }

    #pragma unroll
    for (int i = 0; i < 4; ++i) {
        int m = (wave << 4) + (l4 << 2) + i;
        if (m < lim) {
            int d = sorted[(b << 7) + m];
            #pragma unroll
            for (int c = 0; c < 8; ++c)
                atomicAdd(&agg[(size_t)d * 128 + (c << 4) + l15], acc[c][i]);
        }
    }
}

__global__ __launch_bounds__(256) void k_selfB(
    const unsigned short* __restrict__ hb,
    const unsigned short* __restrict__ Wlbt,
    const float* __restrict__ bias,
    const int* __restrict__ degi,
    float* __restrict__ agg)
{
    __shared__ __align__(16) unsigned char Ws[128 * 256];
    __shared__ float biasS[128];

    int b = blockIdx.x, t = threadIdx.x;
    int n0 = b << 6;
    int lane = t & 63, wave = t >> 6;
    int l15 = lane & 15, l4 = lane >> 4;

    if (t < 128) biasS[t] = bias[t];

    int arow = (wave << 4) + l15;
    int va = n0 + arow; if (va > N_NODES - 1) va = N_NODES - 1;
    const char* ap = (const char*)hb + (size_t)va * 256 + (l4 << 4);
    bf16x8 a0 = *(const bf16x8*)(ap);
    bf16x8 a1 = *(const bf16x8*)(ap + 64);
    bf16x8 a2 = *(const bf16x8*)(ap + 128);
    bf16x8 a3 = *(const bf16x8*)(ap + 192);

    {
        int row = t >> 1, half = t & 1;
        const uint4* g = (const uint4*)((const char*)Wlbt + row * 256);
        unsigned sw = (row & 7) << 4;
        #pragma unroll
        for (int j = 0; j < 8; ++j) {
            int cb = (half << 7) + (j << 4);
            *(uint4*)(Ws + row * 256 + (cb ^ sw)) = g[cb >> 4];
        }
    }
    __syncthreads();

    f32x4 acc[8];
    #pragma unroll
    for (int c = 0; c < 8; ++c) acc[c] = (f32x4)0.0f;

    #pragma unroll
    for (int kk = 0; kk < 4; ++kk) {
        int kb = (kk << 6) + (l4 << 4);
        bf16x8 a = (kk == 0) ? a0 : (kk == 1) ? a1 : (kk == 2) ? a2 : a3;
        #pragma unroll
        for (int c = 0; c < 8; ++c) {
            int brow = (c << 4) + l15;
            bf16x8 bb = *(const bf16x8*)(Ws + brow * 256 + (kb ^ ((brow & 7) << 4)));
            acc[c] = __builtin_amdgcn_mfma_f32_16x16x32_bf16(a, bb, acc[c], 0, 0, 0);
        }
    }

    #pragma unroll
    for (int c = 0; c < 8; ++c) {
        #pragma unroll
        for (int i = 0; i < 4; ++i) {
            int m = (wave << 4) + (l4 << 2) + i;
            int v = n0 + m;
            if (v < N_NODES) {
                int col = (c << 4) + l15;
                float inv = 1.0f / fmaxf((float)degi[v], 1.0f);
                float val = acc[c][i] + agg[(size_t)v * 128 + col] * inv + biasS[col];
                agg[(size_t)v * 128 + col] = fmaxf(val, 0.0f);
            }
        }
    }
}

// ---------------- launch ----------------

extern "C" void kernel_launch(void* const* d_in, const int* in_sizes, int n_in,
                              void* d_out, int out_size, void* d_ws, size_t ws_size,
                              hipStream_t stream)
{
    (void)in_sizes; (void)n_in; (void)out_size;

    const float* h    = (const float*)d_in[0];
    const float* W    = (const float*)d_in[1];
    const float* Wl   = (const float*)d_in[2];
    const float* bias = (const float*)d_in[3];
    const int*   src  = (const int*)d_in[4];
    const int*   dst  = (const int*)d_in[5];
    const int*   rel  = (const int*)d_in[6];
    float* out = (float*)d_out;

    char* ws = (char*)d_ws;
    size_t off = 0;
    auto take = [&](size_t bytes) -> char* {
        char* p = ws + off;
        off += (bytes + 255) & ~(size_t)255;
        return p;
    };
    unsigned short* hb   = (unsigned short*)take((size_t)N_NODES * HDIM * 2);
    unsigned short* Wbt  = (unsigned short*)take((size_t)N_RELS * HDIM * HDIM * 2);
    unsigned short* Wlbt = (unsigned short*)take((size_t)HDIM * HDIM * 2);
    int*   degi    = (int*)take((size_t)N_NODES * 4);
    int*   meta    = (int*)take(1024);
    int*   sorted  = (int*)take((size_t)SORTED_CAP * 4);
    int*   seg     = (int*)take((size_t)(N_NODES + 1) * 4);
    int*   cursor  = (int*)take((size_t)N_NODES * 4);
    int*   bsum    = (int*)take((size_t)NSCAN_BLK * 4);
    int*   boff    = (int*)take((size_t)NSCAN_BLK * 4);
    int2*  edinfo  = (int2*)take((size_t)SORTED_CAP * 8);
    unsigned int*   msg  = (unsigned int*)take((size_t)N_EDGES * HDIM * 2);
    unsigned short* aggB = (unsigned short*)take((size_t)N_NODES * HDIM * 2);
    size_t big_need = off;

    bool pathA = (ws_size >= big_need);

    size_t zbytes = (size_t)((char*)meta - (char*)degi) + 1024;
    (void)hipMemsetAsync(degi, 0, zbytes, stream);

    k_setup<<<2048, 256, 0, stream>>>(h, W, Wl, rel, dst, hb, Wbt, Wlbt, degi, meta);
    k_bsum<<<NSCAN_BLK, 256, 0, stream>>>(degi, bsum);
    k_scan_misc<<<1, 256, 0, stream>>>(meta, bsum, boff, seg);
    k_seg<<<NSCAN_BLK, 256, 0, stream>>>(degi, boff, seg, cursor);
    k_scatter<<<(N_EDGES + 255) / 256, 256, 0, stream>>>(rel, dst, src, meta, sorted, cursor,
                                                         edinfo, pathA ? 0 : 1);

    if (pathA) {
        k_edgeA<<<(MAX_TILES + TPB - 1) / TPB, 512, 0, stream>>>(hb, Wbt, edinfo, meta, msg);
        k_agg<<<(N_NODES + 3) / 4, 256, 0, stream>>>(msg, seg, aggB);
        k_selfA<<<(N_NODES + 63) / 64, 256, 0, stream>>>(hb, Wlbt, bias, aggB, out);
    } else {
        (void)hipMemsetAsync(out, 0, (size_t)N_NODES * HDIM * 4, stream);
        k_edgeB<<<MAX_TILES, 512, 0, stream>>>(hb, Wbt, edinfo, sorted, meta, out);
        k_selfB<<<(N_NODES + 63) / 64, 256, 0, stream>>>(hb, Wlbt, bias, degi, out);
    }
}

// Round 11
// 302.907 us; speedup vs baseline: 1.1106x; 1.0649x over previous
//
#include <hip/hip_runtime.h>
#include <hip/hip_bf16.h>

#define N_NODES 50000
#define N_EDGES 800000
#define HDIM    128
#define N_RELS  24

// rel-padded tile capacity (tiles of 128): 800000 + 24*127 -> 6274 tiles
#define MAX_TILES  6274
#define SORTED_CAP (MAX_TILES * 128)
#define NSCAN_BLK  196          // ceil(50000/256)
#define TPB        2            // 128-edge tiles per k_edgeA block
#define SCAT_BLOCKS 256
#define SCAT_CHUNK  3125        // 256 * 3125 = 800000 exactly

typedef __attribute__((ext_vector_type(8))) short bf16x8;
typedef __attribute__((ext_vector_type(4))) float f32x4;
typedef __attribute__((ext_vector_type(4))) unsigned int u32x4;

static __device__ __forceinline__ float bfbits2f(unsigned u) {
    return __uint_as_float(u << 16);            // bf16 -> f32 exact
}
static __device__ __forceinline__ unsigned f2bfbits(float x) {
    union { __hip_bfloat16 b; unsigned short u; } cv;
    cv.b = __float2bfloat16(x);                 // round-to-nearest
    return (unsigned)cv.u;
}

// msg/aggB rows use a PERMUTED column layout of 64 u32 words:
//   word j (j = l15*4 + c2):  lo = col c2*32 + l15,  hi = col c2*32 + 16 + l15
// k_agg is elementwise so it is layout-agnostic;
// k_selfA inverts: col = c*16+l15  ->  ushort idx = l15*8 + (c>>1)*2 + (c&1).

// ---------------- setup: convert + histogram ----------------

__global__ void k_setup(const float* __restrict__ h,
                        const float* __restrict__ W,
                        const float* __restrict__ Wl,
                        const int* __restrict__ rel,
                        const int* __restrict__ dst,
                        unsigned short* __restrict__ hb,
                        unsigned short* __restrict__ Wbt,
                        unsigned short* __restrict__ Wlbt,
                        int* __restrict__ degi,
                        int* __restrict__ meta)
{
    __shared__ int lh[N_RELS];
    if (threadIdx.x < N_RELS) lh[threadIdx.x] = 0;
    __syncthreads();

    int stride = gridDim.x * blockDim.x;
    int tid = blockIdx.x * blockDim.x + threadIdx.x;

    const float4* h4 = (const float4*)h;
    for (int i = tid; i < N_NODES * HDIM / 4; i += stride) {
        float4 v = h4[i];
        uint2 o;
        o.x = f2bfbits(v.x) | (f2bfbits(v.y) << 16);
        o.y = f2bfbits(v.z) | (f2bfbits(v.w) << 16);
        ((uint2*)hb)[i] = o;
    }
    // Wbt[r][e][k] = W[r][k][e], 4 k at a time
    for (int i = tid; i < N_RELS * HDIM * HDIM / 4; i += stride) {
        int r = i >> 12, rem = i & 4095;
        int e = rem >> 5, kq = rem & 31;
        const float* wp = W + (r << 14) + (kq << 9) + e;
        uint2 o;
        o.x = f2bfbits(wp[0])   | (f2bfbits(wp[128]) << 16);
        o.y = f2bfbits(wp[256]) | (f2bfbits(wp[384]) << 16);
        ((uint2*)Wbt)[i] = o;
    }
    for (int i = tid; i < HDIM * HDIM / 4; i += stride) {
        int e = i >> 5, kq = i & 31;
        const float* wp = Wl + (kq << 9) + e;
        uint2 o;
        o.x = f2bfbits(wp[0])   | (f2bfbits(wp[128]) << 16);
        o.y = f2bfbits(wp[256]) | (f2bfbits(wp[384]) << 16);
        ((uint2*)Wlbt)[i] = o;
    }
    // histogram (degi & meta pre-zeroed by hipMemsetAsync)
    for (int e = tid; e < N_EDGES; e += stride) {
        atomicAdd(&lh[rel[e]], 1);
        atomicAdd(&degi[dst[e]], 1);
    }
    __syncthreads();
    if (threadIdx.x < N_RELS) atomicAdd(&meta[threadIdx.x], lh[threadIdx.x]);
}

// ---------------- hierarchical dst scan (parallel) ----------------

__global__ __launch_bounds__(256) void k_bsum(const int* __restrict__ degi,
                                              int* __restrict__ bsum)
{
    int i = blockIdx.x * 256 + threadIdx.x;
    int v = (i < N_NODES) ? degi[i] : 0;
    #pragma unroll
    for (int d = 32; d > 0; d >>= 1) v += __shfl_down(v, d);
    __shared__ int ws4[4];
    int lane = threadIdx.x & 63, wv = threadIdx.x >> 6;
    if (lane == 0) ws4[wv] = v;
    __syncthreads();
    if (threadIdx.x == 0)
        bsum[blockIdx.x] = ws4[0] + ws4[1] + ws4[2] + ws4[3];
}

// 1 block: parallel scan of the 196 block sums + serial 24-entry rel scan (tiles of 128)
__global__ __launch_bounds__(256) void k_scan_misc(int* __restrict__ meta,
                                                   const int* __restrict__ bsum,
                                                   int* __restrict__ boff,
                                                   int* __restrict__ seg)
{
    __shared__ int wsum[4];
    int t = threadIdx.x;
    int v = (t < NSCAN_BLK) ? bsum[t] : 0;
    int lane = t & 63, wv = t >> 6;
    int x = v;
    #pragma unroll
    for (int d = 1; d < 64; d <<= 1) {
        int y = __shfl_up(x, d);
        if (lane >= d) x += y;
    }
    if (lane == 63) wsum[wv] = x;
    __syncthreads();
    int add = 0;
    for (int w = 0; w < wv; ++w) add += wsum[w];
    if (t < NSCAN_BLK) boff[t] = add + x - v;          // exclusive
    if (t == NSCAN_BLK - 1) seg[N_NODES] = add + x;    // total == N_EDGES

    if (t == 0) {   // rel scan: 24 iterations, trivial. tiles of 128
        int run = 0;
        for (int r = 0; r < N_RELS; ++r) {
            int cnt = meta[r];
            meta[64 + r] = run;          // element base in edinfo[]
            meta[96 + r] = run >> 7;     // tile base (128-edge tiles)
            run += ((cnt + 127) >> 7) << 7;
        }
        meta[64 + N_RELS] = run;
        meta[96 + N_RELS] = run >> 7;    // total tiles
    }
}

__global__ __launch_bounds__(256) void k_seg(const int* __restrict__ degi,
                                             const int* __restrict__ boff,
                                             int* __restrict__ seg,
                                             int* __restrict__ cursor)
{
    int i = blockIdx.x * 256 + threadIdx.x;
    int lane = threadIdx.x & 63, wv = threadIdx.x >> 6;
    int v = (i < N_NODES) ? degi[i] : 0;
    int x = v;
    #pragma unroll
    for (int d = 1; d < 64; d <<= 1) {
        int y = __shfl_up(x, d);
        if (lane >= d) x += y;
    }
    __shared__ int wpart[4];
    if (lane == 63) wpart[wv] = x;
    __syncthreads();
    int add = 0;
    for (int w = 0; w < wv; ++w) add += wpart[w];
    int s = boff[blockIdx.x] + add + x - v;   // exclusive
    if (i < N_NODES) { seg[i] = s; cursor[i] = s; }
}

// ---------------- scatter v2: grid-stride two-pass, low meta contention ----------------

__global__ __launch_bounds__(256) void k_scatter(
    const int* __restrict__ rel,
    const int* __restrict__ dst,
    const int* __restrict__ src,
    int* __restrict__ meta,
    int* __restrict__ sorted,
    int* __restrict__ cursor,
    int2* __restrict__ edinfo,
    int writeSorted)
{
    __shared__ int lh[N_RELS];
    int t = threadIdx.x;
    if (t < N_RELS) lh[t] = 0;
    __syncthreads();

    int e0 = blockIdx.x * SCAT_CHUNK;
    int e1 = e0 + SCAT_CHUNK; if (e1 > N_EDGES) e1 = N_EDGES;

    // pass 1: rel histogram + dst slot atomics (latency overlapped)
    int slots[13];
    int nk = 0;
    for (int e = e0 + t; e < e1; e += 256, ++nk) {
        atomicAdd(&lh[rel[e]], 1);
        slots[nk] = atomicAdd(&cursor[dst[e]], 1);
    }
    __syncthreads();
    if (t < N_RELS) {
        int cnt = lh[t];
        int lb = atomicAdd(&meta[32 + t], cnt);   // 256 per address (was 3125)
        lh[t] = meta[64 + t] + lb;                // absolute position cursor
    }
    __syncthreads();

    // pass 2: placement
    nk = 0;
    for (int e = e0 + t; e < e1; e += 256, ++nk) {
        int pos = atomicAdd(&lh[rel[e]], 1);
        edinfo[pos] = make_int2(src[e], slots[nk]);
        if (writeSorted) sorted[pos] = dst[e];
    }
}

// ---------------- edge GEMM: 512 thr, 128-edge tiles, shared W stage ----------------

__global__ __launch_bounds__(512) void k_edgeA(
    const unsigned short* __restrict__ hb,
    const unsigned short* __restrict__ Wbt,
    const int2* __restrict__ edinfo,
    const int* __restrict__ meta,
    unsigned int* __restrict__ msg)
{
    __shared__ __align__(16) unsigned char Ws[128 * 256];

    int ntiles = meta[96 + N_RELS];
    int b0 = blockIdx.x * TPB;
    if (b0 >= ntiles) return;
    int ntloc = ntiles - b0; if (ntloc > TPB) ntloc = TPB;

    int t = threadIdx.x;
    int lane = t & 63, wave = t >> 6;          // wave 0..7
    int l15 = lane & 15, l4 = lane >> 4;
    int arow = (wave << 4) + l15;              // edge row in tile, 0..127

    int rptr = 0;
    while (b0 >= meta[96 + rptr + 1]) ++rptr;
    int rcur = -1;

    for (int bt = 0; bt < ntloc; ++bt) {
        int b = b0 + bt;
        while (b >= meta[96 + rptr + 1]) ++rptr;
        int r = rptr;
        int lim = meta[r] - ((b - meta[96 + r]) << 7);
        if (lim > 128) lim = 128;

        if (r != rcur) {            // block-uniform (rel boundary)
            if (bt > 0) __syncthreads();      // drain readers of old W
            int row = t >> 2, q = t & 3;      // 4 threads per row, 64B each
            const uint4* g = (const uint4*)((const char*)Wbt + (size_t)r * 32768 + row * 256);
            unsigned sw = (row & 7) << 4;
            #pragma unroll
            for (int j = 0; j < 4; ++j) {
                int cb = (q << 6) + (j << 4);
                *(uint4*)(Ws + row * 256 + (cb ^ sw)) = g[cb >> 4];
            }
            rcur = r;
            __syncthreads();
        }

        // A fragments: coalesced edinfo read + hb row gather (L2/L3 resident)
        int srow = (arow < lim) ? edinfo[(b << 7) + arow].x : 0;
        const char* ap = (const char*)hb + (size_t)srow * 256 + (l4 << 4);
        bf16x8 a0 = *(const bf16x8*)(ap);
        bf16x8 a1 = *(const bf16x8*)(ap + 64);
        bf16x8 a2 = *(const bf16x8*)(ap + 128);
        bf16x8 a3 = *(const bf16x8*)(ap + 192);

        f32x4 acc[8];
        #pragma unroll
        for (int c = 0; c < 8; ++c) acc[c] = (f32x4)0.0f;

        #pragma unroll
        for (int kk = 0; kk < 4; ++kk) {
            int kb = (kk << 6) + (l4 << 4);
            bf16x8 a = (kk == 0) ? a0 : (kk == 1) ? a1 : (kk == 2) ? a2 : a3;
            #pragma unroll
            for (int c = 0; c < 8; ++c) {
                int brow = (c << 4) + l15;
                bf16x8 bb = *(const bf16x8*)(Ws + brow * 256 + (kb ^ ((brow & 7) << 4)));
                acc[c] = __builtin_amdgcn_mfma_f32_16x16x32_bf16(a, bb, acc[c], 0, 0, 0);
            }
        }

        // store: permuted pack, 16B contiguous per lane per edge-row
        #pragma unroll
        for (int i = 0; i < 4; ++i) {
            int m = (wave << 4) + (l4 << 2) + i;
            if (m < lim) {
                int slot = edinfo[(b << 7) + m].y;     // L1-hot
                u32x4 o;
                o.x = f2bfbits(acc[0][i]) | (f2bfbits(acc[1][i]) << 16);
                o.y = f2bfbits(acc[2][i]) | (f2bfbits(acc[3][i]) << 16);
                o.z = f2bfbits(acc[4][i]) | (f2bfbits(acc[5][i]) << 16);
                o.w = f2bfbits(acc[6][i]) | (f2bfbits(acc[7][i]) << 16);
                __builtin_nontemporal_store(o,
                    (u32x4*)((char*)msg + (size_t)slot * 256 + (l15 << 4)));
            }
        }
    }
}

// ---------------- segment mean: one wave per node ----------------

__global__ __launch_bounds__(256) void k_agg(
    const unsigned int* __restrict__ msg,
    const int* __restrict__ seg,
    unsigned short* __restrict__ aggB)
{
    int wv = threadIdx.x >> 6, lane = threadIdx.x & 63;
    int n = blockIdx.x * 4 + wv;
    if (n >= N_NODES) return;
    int s0 = seg[n], s1 = seg[n + 1];
    int deg = s1 - s0;
    int l4 = lane >> 4, l15 = lane & 15;

    float acc[8] = {0, 0, 0, 0, 0, 0, 0, 0};
    const char* base = (const char*)msg + (size_t)s0 * 256;
    int nit = (deg + 3) >> 2;
    for (int it = 0; it < nit; ++it) {
        if (it * 4 + l4 < deg) {
            u32x4 v = __builtin_nontemporal_load(
                (const u32x4*)(base + (size_t)it * 1024 + lane * 16));
            acc[0] += bfbits2f(v.x & 0xffff); acc[1] += bfbits2f(v.x >> 16);
            acc[2] += bfbits2f(v.y & 0xffff); acc[3] += bfbits2f(v.y >> 16);
            acc[4] += bfbits2f(v.z & 0xffff); acc[5] += bfbits2f(v.z >> 16);
            acc[6] += bfbits2f(v.w & 0xffff); acc[7] += bfbits2f(v.w >> 16);
        }
    }
    #pragma unroll
    for (int k = 0; k < 8; ++k) {
        acc[k] += __shfl_xor(acc[k], 16);
        acc[k] += __shfl_xor(acc[k], 32);
    }
    if (l4 == 0) {
        float inv = 1.0f / fmaxf((float)deg, 1.0f);
        u32x4 u;
        u.x = f2bfbits(acc[0] * inv) | (f2bfbits(acc[1] * inv) << 16);
        u.y = f2bfbits(acc[2] * inv) | (f2bfbits(acc[3] * inv) << 16);
        u.z = f2bfbits(acc[4] * inv) | (f2bfbits(acc[5] * inv) << 16);
        u.w = f2bfbits(acc[6] * inv) | (f2bfbits(acc[7] * inv) << 16);
        *(u32x4*)((char*)aggB + (size_t)n * 256 + l15 * 16) = u;
    }
}

// ---------------- self-loop GEMM + agg + bias + relu ----------------

__global__ __launch_bounds__(256) void k_selfA(
    const unsigned short* __restrict__ hb,
    const unsigned short* __restrict__ Wlbt,
    const float* __restrict__ bias,
    const unsigned short* __restrict__ aggB,
    float* __restrict__ out)
{
    __shared__ __align__(16) unsigned char Ws[128 * 256];
    __shared__ float biasS[128];

    int b = blockIdx.x, t = threadIdx.x;
    int n0 = b << 6;
    int lane = t & 63, wave = t >> 6;
    int l15 = lane & 15, l4 = lane >> 4;

    if (t < 128) biasS[t] = bias[t];

    int arow = (wave << 4) + l15;
    int va = n0 + arow; if (va > N_NODES - 1) va = N_NODES - 1;
    const char* ap = (const char*)hb + (size_t)va * 256 + (l4 << 4);
    bf16x8 a0 = *(const bf16x8*)(ap);
    bf16x8 a1 = *(const bf16x8*)(ap + 64);
    bf16x8 a2 = *(const bf16x8*)(ap + 128);
    bf16x8 a3 = *(const bf16x8*)(ap + 192);

    {
        int row = t >> 1, half = t & 1;
        const uint4* g = (const uint4*)((const char*)Wlbt + row * 256);
        unsigned sw = (row & 7) << 4;
        #pragma unroll
        for (int j = 0; j < 8; ++j) {
            int cb = (half << 7) + (j << 4);
            *(uint4*)(Ws + row * 256 + (cb ^ sw)) = g[cb >> 4];
        }
    }
    __syncthreads();

    f32x4 acc[8];
    #pragma unroll
    for (int c = 0; c < 8; ++c) acc[c] = (f32x4)0.0f;

    #pragma unroll
    for (int kk = 0; kk < 4; ++kk) {
        int kb = (kk << 6) + (l4 << 4);
        bf16x8 a = (kk == 0) ? a0 : (kk == 1) ? a1 : (kk == 2) ? a2 : a3;
        #pragma unroll
        for (int c = 0; c < 8; ++c) {
            int brow = (c << 4) + l15;
            bf16x8 bb = *(const bf16x8*)(Ws + brow * 256 + (kb ^ ((brow & 7) << 4)));
            acc[c] = __builtin_amdgcn_mfma_f32_16x16x32_bf16(a, bb, acc[c], 0, 0, 0);
        }
    }

    #pragma unroll
    for (int c = 0; c < 8; ++c) {
        #pragma unroll
        for (int i = 0; i < 4; ++i) {
            int m = (wave << 4) + (l4 << 2) + i;
            int v = n0 + m;
            if (v < N_NODES) {
                int col = (c << 4) + l15;
                // inverse perm read of aggB
                float ag = bfbits2f(aggB[(size_t)v * 128 + l15 * 8 + ((c >> 1) << 1) + (c & 1)]);
                float val = acc[c][i] + ag + biasS[col];
                out[(size_t)v * 128 + col] = fmaxf(val, 0.0f);
            }
        }
    }
}

// ---------------- path B fallback: atomic aggregation into out ----------------

__global__ __launch_bounds__(512) void k_edgeB(
    const unsigned short* __restrict__ hb,
    const unsigned short* __restrict__ Wbt,
    const int2* __restrict__ edinfo,
    const int* __restrict__ sorted,          // holds dst per rel-sorted position
    const int* __restrict__ meta,
    float* __restrict__ agg)
{
    __shared__ __align__(16) unsigned char Ws[128 * 256];

    int b = blockIdx.x;
    if (b >= meta[96 + N_RELS]) return;
    int r = 0;
    while (b >= meta[96 + r + 1]) ++r;
    int lim = meta[r] - ((b - meta[96 + r]) << 7);
    if (lim > 128) lim = 128;

    int t = threadIdx.x;
    int lane = t & 63, wave = t >> 6;
    int l15 = lane & 15, l4 = lane >> 4;
    int arow = (wave << 4) + l15;

    int srow = (arow < lim) ? edinfo[(b << 7) + arow].x : 0;
    const char* ap = (const char*)hb + (size_t)srow * 256 + (l4 << 4);
    bf16x8 a0 = *(const bf16x8*)(ap);
    bf16x8 a1 = *(const bf16x8*)(ap + 64);
    bf16x8 a2 = *(const bf16x8*)(ap + 128);
    bf16x8 a3 = *(const bf16x8*)(ap + 192);

    {
        int row = t >> 2, q = t & 3;
        const uint4* g = (const uint4*)((const char*)Wbt + (size_t)r * 32768 + row * 256);
        unsigned sw = (row & 7) << 4;
        #pragma unroll
        for (int j = 0; j < 4; ++j) {
            int cb = (q << 6) + (j << 4);
            *(uint4*)(Ws + row * 256 + (cb ^ sw)) = g[cb >> 4];
        }
    }
    __syncthreads();

    f32x4 acc[8];
    #pragma unroll
    for (int c = 0; c < 8; ++c) acc[c] = (f32x4)0.0f;

    #pragma unroll
    for (int kk = 0; kk < 4; ++kk) {
        int kb = (kk << 6) + (l4 << 4);
        bf16x8 a = (kk == 0) ? a0 : (kk == 1) ? a1 : (kk == 2) ? a2 : a3;
        #pragma unroll
        for (int c = 0; c < 8; ++c) {
            int brow = (c << 4) + l15;
            bf16x8 bb = *(const bf16x8*)(Ws + brow * 256 + (kb ^ ((brow & 7) << 4)));
            acc[c] = __builtin_amdgcn_mfma_f32_16x16x32_bf16(a, bb, acc[c], 0, 0, 0);
        }
    }

    #pragma unroll
    for (int i = 0; i < 4; ++i) {
        int m = (wave << 4) + (l4 << 2) + i;
        if (m < lim) {
            int d = sorted[(b << 7) + m];
            #pragma unroll
            for (int c = 0; c < 8; ++c)
                atomicAdd(&agg[(size_t)d * 128 + (c << 4) + l15], acc[c][i]);
        }
    }
}

__global__ __launch_bounds__(256) void k_selfB(
    const unsigned short* __restrict__ hb,
    const unsigned short* __restrict__ Wlbt,
    const float* __restrict__ bias,
    const int* __restrict__ degi,
    float* __restrict__ agg)
{
    __shared__ __align__(16) unsigned char Ws[128 * 256];
    __shared__ float biasS[128];

    int b = blockIdx.x, t = threadIdx.x;
    int n0 = b << 6;
    int lane = t & 63, wave = t >> 6;
    int l15 = lane & 15, l4 = lane >> 4;

    if (t < 128) biasS[t] = bias[t];

    int arow = (wave << 4) + l15;
    int va = n0 + arow; if (va > N_NODES - 1) va = N_NODES - 1;
    const char* ap = (const char*)hb + (size_t)va * 256 + (l4 << 4);
    bf16x8 a0 = *(const bf16x8*)(ap);
    bf16x8 a1 = *(const bf16x8*)(ap + 64);
    bf16x8 a2 = *(const bf16x8*)(ap + 128);
    bf16x8 a3 = *(const bf16x8*)(ap + 192);

    {
        int row = t >> 1, half = t & 1;
        const uint4* g = (const uint4*)((const char*)Wlbt + row * 256);
        unsigned sw = (row & 7) << 4;
        #pragma unroll
        for (int j = 0; j < 8; ++j) {
            int cb = (half << 7) + (j << 4);
            *(uint4*)(Ws + row * 256 + (cb ^ sw)) = g[cb >> 4];
        }
    }
    __syncthreads();

    f32x4 acc[8];
    #pragma unroll
    for (int c = 0; c < 8; ++c) acc[c] = (f32x4)0.0f;

    #pragma unroll
    for (int kk = 0; kk < 4; ++kk) {
        int kb = (kk << 6) + (l4 << 4);
        bf16x8 a = (kk == 0) ? a0 : (kk == 1) ? a1 : (kk == 2) ? a2 : a3;
        #pragma unroll
        for (int c = 0; c < 8; ++c) {
            int brow = (c << 4) + l15;
            bf16x8 bb = *(const bf16x8*)(Ws + brow * 256 + (kb ^ ((brow & 7) << 4)));
            acc[c] = __builtin_amdgcn_mfma_f32_16x16x32_bf16(a, bb, acc[c], 0, 0, 0);
        }
    }

    #pragma unroll
    for (int c = 0; c < 8; ++c) {
        #pragma unroll
        for (int i = 0; i < 4; ++i) {
            int m = (wave << 4) + (l4 << 2) + i;
            int v = n0 + m;
            if (v < N_NODES) {
                int col = (c << 4) + l15;
                float inv = 1.0f / fmaxf((float)degi[v], 1.0f);
                float val = acc[c][i] + agg[(size_t)v * 128 + col] * inv + biasS[col];
                agg[(size_t)v * 128 + col] = fmaxf(val, 0.0f);
            }
        }
    }
}

// ---------------- launch ----------------

extern "C" void kernel_launch(void* const* d_in, const int* in_sizes, int n_in,
                              void* d_out, int out_size, void* d_ws, size_t ws_size,
                              hipStream_t stream)
{
    (void)in_sizes; (void)n_in; (void)out_size;

    const float* h    = (const float*)d_in[0];
    const float* W    = (const float*)d_in[1];
    const float* Wl   = (const float*)d_in[2];
    const float* bias = (const float*)d_in[3];
    const int*   src  = (const int*)d_in[4];
    const int*   dst  = (const int*)d_in[5];
    const int*   rel  = (const int*)d_in[6];
    float* out = (float*)d_out;

    char* ws = (char*)d_ws;
    size_t off = 0;
    auto take = [&](size_t bytes) -> char* {
        char* p = ws + off;
        off += (bytes + 255) & ~(size_t)255;
        return p;
    };
    unsigned short* hb   = (unsigned short*)take((size_t)N_NODES * HDIM * 2);
    unsigned short* Wbt  = (unsigned short*)take((size_t)N_RELS * HDIM * HDIM * 2);
    unsigned short* Wlbt = (unsigned short*)take((size_t)HDIM * HDIM * 2);
    int*   degi    = (int*)take((size_t)N_NODES * 4);
    int*   meta    = (int*)take(1024);
    int*   sorted  = (int*)take((size_t)SORTED_CAP * 4);
    int*   seg     = (int*)take((size_t)(N_NODES + 1) * 4);
    int*   cursor  = (int*)take((size_t)N_NODES * 4);
    int*   bsum    = (int*)take((size_t)NSCAN_BLK * 4);
    int*   boff    = (int*)take((size_t)NSCAN_BLK * 4);
    int2*  edinfo  = (int2*)take((size_t)SORTED_CAP * 8);
    unsigned int*   msg  = (unsigned int*)take((size_t)N_EDGES * HDIM * 2);
    unsigned short* aggB = (unsigned short*)take((size_t)N_NODES * HDIM * 2);
    size_t big_need = off;

    bool pathA = (ws_size >= big_need);

    size_t zbytes = (size_t)((char*)meta - (char*)degi) + 1024;
    (void)hipMemsetAsync(degi, 0, zbytes, stream);

    k_setup<<<2048, 256, 0, stream>>>(h, W, Wl, rel, dst, hb, Wbt, Wlbt, degi, meta);
    k_bsum<<<NSCAN_BLK, 256, 0, stream>>>(degi, bsum);
    k_scan_misc<<<1, 256, 0, stream>>>(meta, bsum, boff, seg);
    k_seg<<<NSCAN_BLK, 256, 0, stream>>>(degi, boff, seg, cursor);
    k_scatter<<<SCAT_BLOCKS, 256, 0, stream>>>(rel, dst, src, meta, sorted, cursor,
                                               edinfo, pathA ? 0 : 1);

    if (pathA) {
        k_edgeA<<<(MAX_TILES + TPB - 1) / TPB, 512, 0, stream>>>(hb, Wbt, edinfo, meta, msg);
        k_agg<<<(N_NODES + 3) / 4, 256, 0, stream>>>(msg, seg, aggB);
        k_selfA<<<(N_NODES + 63) / 64, 256, 0, stream>>>(hb, Wlbt, bias, aggB, out);
    } else {
        (void)hipMemsetAsync(out, 0, (size_t)N_NODES * HDIM * 4, stream);
        k_edgeB<<<MAX_TILES, 512, 0, stream>>>(hb, Wbt, edinfo, sorted, meta, out);
        k_selfB<<<(N_NODES + 63) / 64, 256, 0, stream>>>(hb, Wlbt, bias, degi, out);
    }
}